// Round 2
// baseline (430.488 us; speedup 1.0000x reference)
//
#include <hip/hip_runtime.h>

typedef unsigned int uint;
typedef __bf16 bf16_t;
typedef bf16_t bf16x8 __attribute__((ext_vector_type(8)));
typedef float floatx4 __attribute__((ext_vector_type(4)));

struct __align__(8) us4 { unsigned short x, y, z, w; };

__device__ __forceinline__ unsigned short f2b(float f) {
    unsigned u = __float_as_uint(f);
    u = u + 0x7FFFu + ((u >> 16) & 1u);   // RNE
    return (unsigned short)(u >> 16);
}
__device__ __forceinline__ float b2f(unsigned short h) {
    return __uint_as_float(((unsigned)h) << 16);
}

// async global->LDS, 16B per lane; LDS dest is wave-uniform base + lane*16
__device__ __forceinline__ void g2l16(const void* g, void* l) {
    __builtin_amdgcn_global_load_lds((__attribute__((address_space(1))) void*)g,
                                     (__attribute__((address_space(3))) void*)l,
                                     16, 0, 0);
}

__device__ __forceinline__ float wave_max(float v) {
#pragma unroll
    for (int m = 32; m > 0; m >>= 1) v = fmaxf(v, __shfl_xor(v, m));
    return v;
}
__device__ __forceinline__ float wave_sum(float v) {
#pragma unroll
    for (int m = 32; m > 0; m >>= 1) v += __shfl_xor(v, m);
    return v;
}

// ---------------------------------------------------------------------------
// gemm_n512: O[m,n] = sum_k A[m,k] * B[n,k], n covers ALL 512 columns per block
// (B has exactly 512 rows). BM=128, BN=512, BK=32. 512 threads = 8 waves (2x4),
// wave-tile 64x128 = 4x8 frags of 16x16x32 MFMA. A is fetched from HBM exactly
// once across the grid (no n-tile re-read); B stays L2-resident (<=0.5 MB).
// MODE 0: bf16 store O[m*ldo+n]
// MODE 1: bf16 TRANSPOSED store into OT[b, n, m%seqN]  (b = m0/seqN)
// MODE 2: bf16 store of (acc + R[m*ldo+n])   (residual add)
// MODE 3: f32  store of (acc + R[m*ldo+n])
// ---------------------------------------------------------------------------
template <int MODE>
__global__ __launch_bounds__(512, 2) void gemm_n512(
    const unsigned short* __restrict__ A, const unsigned short* __restrict__ B,
    void* __restrict__ O, const unsigned short* __restrict__ R,
    int K, int lda, int ldb, int ldo,
    long long sA, long long sB, long long sO, long long sR, int seqN)
{
    __shared__ __attribute__((aligned(16))) unsigned short As[128 * 32];
    __shared__ __attribute__((aligned(16))) unsigned short Bs[512 * 32];

    const int bz = blockIdx.z;
    const unsigned short* Ab = A + (long long)bz * sA;
    const unsigned short* Bb = B + (long long)bz * sB;
    const int m0 = blockIdx.x * 128;
    const int tid = threadIdx.x;
    const int l = tid & 63;
    const int w = tid >> 6;
    const int wm = (w >> 2) * 64;    // 2 wave-rows
    const int wn = (w & 3) * 128;    // 4 wave-cols

    // staging: thread t covers row (t>>2), 16B chunk (t&3) of the 64B k-row
    const int srow = tid >> 2;            // 0..127
    const int scol = (tid & 3) * 8;
    const unsigned short* ga = Ab + (long long)(m0 + srow) * lda + scol;
    const unsigned short* gb = Bb + (long long)srow * ldb + scol;   // rows 0..127 (+128c)
    unsigned short* la = As + tid * 8;
    unsigned short* lb = Bs + tid * 8;    // call c adds 4096 shorts

    const int fr = l & 15;
    const int kq = (l >> 4) * 8;

    floatx4 acc[4][8] = {};

    for (int kt = 0; kt < K; kt += 32) {
        __syncthreads();                       // previous tile fully consumed
        g2l16(ga, la);
        g2l16(gb,                  lb);
        g2l16(gb + 128LL * ldb,    lb + 4096);
        g2l16(gb + 256LL * ldb,    lb + 8192);
        g2l16(gb + 384LL * ldb,    lb + 12288);
        ga += 32; gb += 32;
        __syncthreads();                       // staging complete

        bf16x8 af[4], bfr[8];
#pragma unroll
        for (int i = 0; i < 4; ++i)
            af[i] = *(const bf16x8*)(As + (wm + i * 16 + fr) * 32 + kq);
#pragma unroll
        for (int j = 0; j < 8; ++j)
            bfr[j] = *(const bf16x8*)(Bs + (wn + j * 16 + fr) * 32 + kq);
#pragma unroll
        for (int i = 0; i < 4; ++i)
#pragma unroll
            for (int j = 0; j < 8; ++j)
                acc[i][j] = __builtin_amdgcn_mfma_f32_16x16x32_bf16(
                    af[i], bfr[j], acc[i][j], 0, 0, 0);
    }

    // C/D layout (verified m89/m91): col = lane&15, row = (lane>>4)*4 + reg
    const int col = l & 15;
    const int rbase = (l >> 4) * 4;

    if constexpr (MODE == 1) {
        unsigned short* Ot = (unsigned short*)O;
        const int b = m0 / seqN;
        const int mqb = m0 - b * seqN;
#pragma unroll
        for (int i = 0; i < 4; ++i) {
#pragma unroll
            for (int j = 0; j < 8; ++j) {
                int gn = wn + j * 16 + col;
                int mq = mqb + wm + i * 16 + rbase;   // 4 consecutive m per lane
                us4 pk = { f2b(acc[i][j][0]), f2b(acc[i][j][1]),
                           f2b(acc[i][j][2]), f2b(acc[i][j][3]) };
                *(us4*)(Ot + ((long long)b * ldo + gn) * seqN + mq) = pk;
            }
        }
    } else {
#pragma unroll
        for (int i = 0; i < 4; ++i) {
#pragma unroll
            for (int j = 0; j < 8; ++j) {
                int gn = wn + j * 16 + col;
                int gmb = m0 + wm + i * 16 + rbase;
#pragma unroll
                for (int r = 0; r < 4; ++r) {
                    long long idx = (long long)(gmb + r) * ldo + gn;
                    float v = acc[i][j][r];
                    if constexpr (MODE == 0) {
                        ((unsigned short*)O + bz * sO)[idx] = f2b(v);
                    } else if constexpr (MODE == 2) {
                        const unsigned short* Rb = R + bz * sR;
                        ((unsigned short*)O + bz * sO)[idx] = f2b(v + b2f(Rb[idx]));
                    } else {
                        const unsigned short* Rb = R + bz * sR;
                        ((float*)O + bz * sO)[idx] = v + b2f(Rb[idx]);
                    }
                }
            }
        }
    }
}

// ---------------------------------------------------------------------------
// ctx_gemm: ctxT[b,e,d] = sum_n vT[b,e,n] * kT[b,d,n].  K=4096, out 512x512.
// 64x64 tiles, grid (batch=8, mtile=8, ntile=8): batch is the FASTEST grid dim
// so block linear index % 8 == batch -> all 64 blocks of a batch land on one
// XCD (round-robin dispatch heuristic) and the K-stripe working set (~64 KB)
// re-reads hit XCD-local L2 instead of HBM.
// ---------------------------------------------------------------------------
__global__ __launch_bounds__(256) void ctx_gemm(
    const unsigned short* __restrict__ V, const unsigned short* __restrict__ Kt,
    unsigned short* __restrict__ Ct)
{
    __shared__ __attribute__((aligned(16))) unsigned short As[64 * 32];
    __shared__ __attribute__((aligned(16))) unsigned short Bs[64 * 32];

    const int b  = blockIdx.x;          // batch (fastest -> XCD pin)
    const int m0 = blockIdx.y * 64;
    const int n0 = blockIdx.z * 64;
    const unsigned short* Ab = V  + (long long)b * 512 * 4096;
    const unsigned short* Bb = Kt + (long long)b * 512 * 4096;

    const int tid = threadIdx.x;
    const int l = tid & 63;
    const int w = tid >> 6;
    const int wm = (w >> 1) * 32;
    const int wn = (w & 1) * 32;

    const int srow = tid >> 2;          // 0..63
    const int scol = (tid & 3) * 8;
    const unsigned short* ga = Ab + (long long)(m0 + srow) * 4096 + scol;
    const unsigned short* gb = Bb + (long long)(n0 + srow) * 4096 + scol;
    unsigned short* la = As + tid * 8;
    unsigned short* lb = Bs + tid * 8;

    const int fr = l & 15;
    const int kq = (l >> 4) * 8;

    floatx4 acc[2][2] = {};

    for (int kt = 0; kt < 4096; kt += 32) {
        __syncthreads();
        g2l16(ga, la);
        g2l16(gb, lb);
        ga += 32; gb += 32;
        __syncthreads();

        bf16x8 af[2], bfr[2];
#pragma unroll
        for (int i = 0; i < 2; ++i) {
            af[i]  = *(const bf16x8*)(As + (wm + i * 16 + fr) * 32 + kq);
            bfr[i] = *(const bf16x8*)(Bs + (wn + i * 16 + fr) * 32 + kq);
        }
#pragma unroll
        for (int i = 0; i < 2; ++i)
#pragma unroll
            for (int j = 0; j < 2; ++j)
                acc[i][j] = __builtin_amdgcn_mfma_f32_16x16x32_bf16(
                    af[i], bfr[j], acc[i][j], 0, 0, 0);
    }

    const int col = l & 15;
    const int rbase = (l >> 4) * 4;
    unsigned short* Ob = Ct + (long long)b * 512 * 512;
#pragma unroll
    for (int i = 0; i < 2; ++i)
#pragma unroll
        for (int j = 0; j < 2; ++j)
#pragma unroll
            for (int r = 0; r < 4; ++r) {
                int gm = m0 + wm + i * 16 + rbase + r;
                int gn = n0 + wn + j * 16 + col;
                Ob[(long long)gm * 512 + gn] = f2b(acc[i][j][r]);
            }
}

// ---------------------------------------------------------------------------
// conversions
// ---------------------------------------------------------------------------
__global__ __launch_bounds__(256) void f32_to_bf16_k(const float* __restrict__ in,
                                                     unsigned short* __restrict__ out)
{
    long long i = ((long long)blockIdx.x * 256 + threadIdx.x) * 4;
    float4 v = *(const float4*)(in + i);
    us4 o = { f2b(v.x), f2b(v.y), f2b(v.z), f2b(v.w) };
    *(us4*)(out + i) = o;
}

struct WPtrs { const float* in[5]; unsigned short* out[5]; };
__global__ __launch_bounds__(256) void conv_weights(WPtrs p)
{
    int which = blockIdx.y;
    long long i = ((long long)blockIdx.x * 256 + threadIdx.x) * 4;
    float4 v = *(const float4*)(p.in[which] + i);
    us4 o = { f2b(v.x), f2b(v.y), f2b(v.z), f2b(v.w) };
    *(us4*)(p.out[which] + i) = o;
}

// ---------------------------------------------------------------------------
// softmax over rows of length 512, in place, times `scale` (q path)
// ---------------------------------------------------------------------------
__global__ __launch_bounds__(256) void softmax_row512(unsigned short* __restrict__ q,
                                                      float scale)
{
    __shared__ float red[8];
    unsigned short* p = q + (long long)blockIdx.x * 512;
    int t = threadIdx.x;
    uint v = *(const uint*)(p + 2 * t);
    float a = b2f((unsigned short)(v & 0xffff));
    float b = b2f((unsigned short)(v >> 16));
    float mx = wave_max(fmaxf(a, b));
    int w = t >> 6;
    if ((t & 63) == 0) red[w] = mx;
    __syncthreads();
    mx = fmaxf(fmaxf(red[0], red[1]), fmaxf(red[2], red[3]));
    float ea = __expf(a - mx), eb = __expf(b - mx);
    float s = wave_sum(ea + eb);
    if ((t & 63) == 0) red[4 + w] = s;
    __syncthreads();
    s = red[4] + red[5] + red[6] + red[7];
    float inv = scale / s;
    uint o = (uint)f2b(ea * inv) | ((uint)f2b(eb * inv) << 16);
    *(uint*)(p + 2 * t) = o;
}

// ---------------------------------------------------------------------------
// softmax over rows of length 4096, in place (k path, rows = (b,c) of kT)
// ---------------------------------------------------------------------------
__global__ __launch_bounds__(256) void softmax_row4096(unsigned short* __restrict__ kk)
{
    __shared__ float red[8];
    unsigned short* p = kk + (long long)blockIdx.x * 4096;
    int t = threadIdx.x;
    uint4 v0 = *(const uint4*)(p + 16 * t);
    uint4 v1 = *(const uint4*)(p + 16 * t + 8);
    uint u[8] = { v0.x, v0.y, v0.z, v0.w, v1.x, v1.y, v1.z, v1.w };
    float f[16];
#pragma unroll
    for (int i = 0; i < 8; ++i) {
        f[2 * i]     = b2f((unsigned short)(u[i] & 0xffff));
        f[2 * i + 1] = b2f((unsigned short)(u[i] >> 16));
    }
    float mx = f[0];
#pragma unroll
    for (int i = 1; i < 16; ++i) mx = fmaxf(mx, f[i]);
    mx = wave_max(mx);
    int w = t >> 6;
    if ((t & 63) == 0) red[w] = mx;
    __syncthreads();
    mx = fmaxf(fmaxf(red[0], red[1]), fmaxf(red[2], red[3]));
    float s = 0.f;
#pragma unroll
    for (int i = 0; i < 16; ++i) { f[i] = __expf(f[i] - mx); s += f[i]; }
    s = wave_sum(s);
    if ((t & 63) == 0) red[4 + w] = s;
    __syncthreads();
    s = red[4] + red[5] + red[6] + red[7];
    float inv = 1.f / s;
    uint o[8];
#pragma unroll
    for (int i = 0; i < 8; ++i)
        o[i] = (uint)f2b(f[2 * i] * inv) | ((uint)f2b(f[2 * i + 1] * inv) << 16);
    *(uint4*)(p + 16 * t)     = make_uint4(o[0], o[1], o[2], o[3]);
    *(uint4*)(p + 16 * t + 8) = make_uint4(o[4], o[5], o[6], o[7]);
}

// ---------------------------------------------------------------------------
extern "C" void kernel_launch(void* const* d_in, const int* in_sizes, int n_in,
                              void* d_out, int out_size, void* d_ws, size_t ws_size,
                              hipStream_t stream)
{
    (void)in_sizes; (void)n_in; (void)out_size; (void)ws_size;
    const float* x  = (const float*)d_in[0];
    const float* Wq = (const float*)d_in[1];
    const float* Wk = (const float*)d_in[2];
    const float* Wv = (const float*)d_in[3];
    const float* W1 = (const float*)d_in[4];
    const float* W2 = (const float*)d_in[5];
    float* out = (float*)d_out;

    const int Bn = 8, N = 4096, C = 512;
    const long long M  = (long long)Bn * N;   // 32768
    const long long XE = M * C;               // 16,777,216 elements

    char* ws = (char*)d_ws;
    size_t off = 0;
    auto carve = [&](size_t bytes) -> void* {
        void* p = ws + off;
        off += (bytes + 255) & ~(size_t)255;
        return p;
    };

    unsigned short* xb   = (unsigned short*)carve(XE * 2);
    unsigned short* wqb  = (unsigned short*)carve((size_t)C * C * 2);
    unsigned short* wkb  = (unsigned short*)carve((size_t)C * C * 2);
    unsigned short* wvb  = (unsigned short*)carve((size_t)C * C * 2);
    unsigned short* w1b  = (unsigned short*)carve((size_t)C * C * 2);
    unsigned short* w2b  = (unsigned short*)carve((size_t)C * C * 2);
    unsigned short* q    = (unsigned short*)carve(XE * 2);
    unsigned short* kT   = (unsigned short*)carve(XE * 2);   // [b, c, n]
    unsigned short* vT   = (unsigned short*)carve(XE * 2);   // [b, c, n]
    unsigned short* ctxT = (unsigned short*)carve((size_t)Bn * C * C * 2); // [b, e, d]
    unsigned short* xr = kT;   // alias: kT dead after ctx gemm
    unsigned short* h  = vT;   // alias: vT dead after ctx gemm

    // dtype conversions
    f32_to_bf16_k<<<dim3((unsigned)(XE / 1024)), dim3(256), 0, stream>>>(x, xb);
    WPtrs wp = { { Wq, Wk, Wv, W1, W2 }, { wqb, wkb, wvb, w1b, w2b } };
    conv_weights<<<dim3((C * C) / 1024, 5), dim3(256), 0, stream>>>(wp);

    // q = x@Wq.T ; kT = (x@Wk.T)^T ; vT = (x@Wv.T)^T   (transposed epilogue)
    gemm_n512<0><<<dim3(M / 128, 1, 1), 512, 0, stream>>>(
        xb, wqb, q, nullptr, C, C, C, C, 0, 0, 0, 0, 0);
    gemm_n512<1><<<dim3(M / 128, 1, 1), 512, 0, stream>>>(
        xb, wkb, kT, nullptr, C, C, C, C, 0, 0, 0, 0, N);
    gemm_n512<1><<<dim3(M / 128, 1, 1), 512, 0, stream>>>(
        xb, wvb, vT, nullptr, C, C, C, C, 0, 0, 0, 0, N);

    // softmaxes (in place)
    softmax_row512<<<dim3((unsigned)M), 256, 0, stream>>>(q, 0.044194173824159216f);
    softmax_row4096<<<dim3(Bn * C), 256, 0, stream>>>(kT);

    // ctxT[b,e,d] = sum_n vT[b,e,n] * kT[b,d,n]   (XCD-pinned, K=4096)
    ctx_gemm<<<dim3(Bn, C / 64, C / 64), 256, 0, stream>>>(vT, kT, ctxT);

    // xr[b,n,e] = sum_d q[b,n,d] * ctxT[b,e,d] + x[b,n,e]
    gemm_n512<2><<<dim3(N / 128, 1, Bn), 512, 0, stream>>>(
        q, ctxT, xr, xb, C, C, C, C,
        (long long)N * C, (long long)C * C, (long long)N * C, (long long)N * C, 0);

    // h = xr @ W1.T
    gemm_n512<0><<<dim3(M / 128, 1, 1), 512, 0, stream>>>(
        xr, w1b, h, nullptr, C, C, C, C, 0, 0, 0, 0, 0);

    // out = h @ W2.T + xr   (fp32 output)
    gemm_n512<3><<<dim3(M / 128, 1, 1), 512, 0, stream>>>(
        h, w2b, out, xr, C, C, C, C, 0, 0, 0, 0, 0);
}

// Round 3
// 381.761 us; speedup vs baseline: 1.1276x; 1.1276x over previous
//
#include <hip/hip_runtime.h>

typedef unsigned int uint;
typedef __bf16 bf16_t;
typedef bf16_t bf16x8 __attribute__((ext_vector_type(8)));
typedef float floatx4 __attribute__((ext_vector_type(4)));

struct __align__(8) us4 { unsigned short x, y, z, w; };

__device__ __forceinline__ unsigned short f2b(float f) {
    unsigned u = __float_as_uint(f);
    u = u + 0x7FFFu + ((u >> 16) & 1u);   // RNE
    return (unsigned short)(u >> 16);
}
__device__ __forceinline__ float b2f(unsigned short h) {
    return __uint_as_float(((unsigned)h) << 16);
}

// async global->LDS, 16B per lane; LDS dest is wave-uniform base + lane*16
__device__ __forceinline__ void g2l16(const void* g, void* l) {
    __builtin_amdgcn_global_load_lds((__attribute__((address_space(1))) void*)g,
                                     (__attribute__((address_space(3))) void*)l,
                                     16, 0, 0);
}

__device__ __forceinline__ float wave_max(float v) {
#pragma unroll
    for (int m = 32; m > 0; m >>= 1) v = fmaxf(v, __shfl_xor(v, m));
    return v;
}
__device__ __forceinline__ float wave_sum(float v) {
#pragma unroll
    for (int m = 32; m > 0; m >>= 1) v += __shfl_xor(v, m);
    return v;
}

// ---------------------------------------------------------------------------
// gemm128: O[m,n] = sum_k A[m,k] * B[n,k]  (both row-major, K inner)
// 128x128 tile, BK=32, 256 threads (4 waves 2x2), wave 64x64 = 4x4 MFMA frags.
// Grid: x = n-tile (FASTEST -> 4 consecutive blocks share one A-stripe in
// L2/L3), y = m-tile, z = batch. __launch_bounds__(256,4): 4 blocks/CU so
// barrier drains of one block overlap compute of three others.
// MODE 0: bf16 store O[m*ldo+n]
// MODE 2: bf16 store of (acc + R[m*ldo+n])
// MODE 3: f32  store of (acc + R[m*ldo+n])
// MODE 4: fused qkv. B = concat(Wq,Wk,Wv) [1536x512]. n<512 -> plain bf16
//         store to O (=q). 512..1023 -> transposed store to O2 (=kT[b,c,n]).
//         >=1024 -> transposed store to O3 (=vT[b,c,n]).  (N=4096 rows/batch)
// ---------------------------------------------------------------------------
template <int MODE>
__global__ __launch_bounds__(256, 4) void gemm128(
    const unsigned short* __restrict__ A, const unsigned short* __restrict__ B,
    void* __restrict__ O, const unsigned short* __restrict__ R,
    unsigned short* __restrict__ O2, unsigned short* __restrict__ O3,
    int K, int lda, int ldb, int ldo,
    long long sA, long long sB, long long sO, long long sR)
{
    __shared__ __attribute__((aligned(16))) unsigned short As[128 * 32];
    __shared__ __attribute__((aligned(16))) unsigned short Bs[128 * 32];

    const int bz = blockIdx.z;
    const unsigned short* Ab = A + (long long)bz * sA;
    const unsigned short* Bb = B + (long long)bz * sB;
    const int n0 = blockIdx.x * 128;
    const int m0 = blockIdx.y * 128;
    const int tid = threadIdx.x;
    const int l = tid & 63;
    const int w = tid >> 6;
    const int wm = (w >> 1) * 64;
    const int wn = (w & 1) * 64;

    // staging: thread t covers row (t>>2), 16B chunk (t&3) of the 64B k-row
    const int srow = tid >> 2;
    const int scol = (tid & 3) * 8;
    const unsigned short* ga = Ab + (long long)(m0 + srow) * lda + scol;
    const unsigned short* gb = Bb + (long long)(n0 + srow) * ldb + scol;
    unsigned short* la = As + tid * 8;
    unsigned short* lb = Bs + tid * 8;

    const int fr = l & 15;
    const int kq = (l >> 4) * 8;

    floatx4 acc[4][4] = {};

    for (int kt = 0; kt < K; kt += 32) {
        __syncthreads();                       // previous tile fully consumed
        g2l16(ga, la);
        g2l16(ga + (long long)64 * lda, la + 64 * 32);
        g2l16(gb, lb);
        g2l16(gb + (long long)64 * ldb, lb + 64 * 32);
        ga += 32; gb += 32;
        __syncthreads();                       // staging complete

        bf16x8 af[4], bfr[4];
#pragma unroll
        for (int i = 0; i < 4; ++i) {
            af[i]  = *(const bf16x8*)(As + (wm + i * 16 + fr) * 32 + kq);
            bfr[i] = *(const bf16x8*)(Bs + (wn + i * 16 + fr) * 32 + kq);
        }
#pragma unroll
        for (int i = 0; i < 4; ++i)
#pragma unroll
            for (int j = 0; j < 4; ++j)
                acc[i][j] = __builtin_amdgcn_mfma_f32_16x16x32_bf16(
                    af[i], bfr[j], acc[i][j], 0, 0, 0);
    }

    // C/D layout (verified m89/m91): col = lane&15, row = (lane>>4)*4 + reg
    const int col = l & 15;
    const int rbase = (l >> 4) * 4;

    if constexpr (MODE == 4) {
        if (n0 < 512) {
            unsigned short* Oq = (unsigned short*)O;
#pragma unroll
            for (int i = 0; i < 4; ++i)
#pragma unroll
                for (int j = 0; j < 4; ++j) {
                    int gn = n0 + wn + j * 16 + col;
                    int gmb = m0 + wm + i * 16 + rbase;
#pragma unroll
                    for (int r = 0; r < 4; ++r)
                        Oq[(long long)(gmb + r) * 512 + gn] = f2b(acc[i][j][r]);
                }
        } else {
            unsigned short* T = (n0 < 1024) ? O2 : O3;
            const int nbase = (n0 < 1024) ? 512 : 1024;
            const int b = m0 >> 12;          // m0 / 4096
            const int mq0 = m0 & 4095;
#pragma unroll
            for (int i = 0; i < 4; ++i)
#pragma unroll
                for (int j = 0; j < 4; ++j) {
                    int gn = n0 + wn + j * 16 + col - nbase;
                    int mq = mq0 + wm + i * 16 + rbase;
                    us4 pk = { f2b(acc[i][j][0]), f2b(acc[i][j][1]),
                               f2b(acc[i][j][2]), f2b(acc[i][j][3]) };
                    *(us4*)(T + ((long long)b * 512 + gn) * 4096 + mq) = pk;
                }
        }
    } else {
#pragma unroll
        for (int i = 0; i < 4; ++i)
#pragma unroll
            for (int j = 0; j < 4; ++j) {
                int gn = n0 + wn + j * 16 + col;
                int gmb = m0 + wm + i * 16 + rbase;
#pragma unroll
                for (int r = 0; r < 4; ++r) {
                    long long idx = (long long)(gmb + r) * ldo + gn;
                    float v = acc[i][j][r];
                    if constexpr (MODE == 0) {
                        ((unsigned short*)O + bz * sO)[idx] = f2b(v);
                    } else if constexpr (MODE == 2) {
                        const unsigned short* Rb = R + bz * sR;
                        ((unsigned short*)O + bz * sO)[idx] = f2b(v + b2f(Rb[idx]));
                    } else {
                        const unsigned short* Rb = R + bz * sR;
                        ((float*)O + bz * sO)[idx] = v + b2f(Rb[idx]);
                    }
                }
            }
    }
}

// ---------------------------------------------------------------------------
// ctx split-K gemm: P[(b,s),mt,nt] partial of ctxT[b,e,d] = sum_n vT[b,e,n]*
// kT[b,d,n]. 128x128 tile, BK=32, split-K=4 (K=1024 per block).
// Grid (4 n-tiles fastest, 4 m-tiles, 32 = b*4+s) = 512 blocks -> 2/CU.
// Partials are fp32, non-overlapping, written to scratch (d_out).
// ---------------------------------------------------------------------------
__global__ __launch_bounds__(256, 4) void ctx_gemm_sk(
    const unsigned short* __restrict__ V, const unsigned short* __restrict__ Kt,
    float* __restrict__ P)
{
    __shared__ __attribute__((aligned(16))) unsigned short As[128 * 32];
    __shared__ __attribute__((aligned(16))) unsigned short Bs[128 * 32];

    const int z = blockIdx.z;
    const int b = z >> 2;
    const int s = z & 3;
    const int n0 = blockIdx.x * 128;
    const int m0 = blockIdx.y * 128;
    const unsigned short* Ab = V  + (long long)b * 512 * 4096 + s * 1024;
    const unsigned short* Bb = Kt + (long long)b * 512 * 4096 + s * 1024;

    const int tid = threadIdx.x;
    const int l = tid & 63;
    const int w = tid >> 6;
    const int wm = (w >> 1) * 64;
    const int wn = (w & 1) * 64;

    const int srow = tid >> 2;
    const int scol = (tid & 3) * 8;
    const unsigned short* ga = Ab + (long long)(m0 + srow) * 4096 + scol;
    const unsigned short* gb = Bb + (long long)(n0 + srow) * 4096 + scol;
    unsigned short* la = As + tid * 8;
    unsigned short* lb = Bs + tid * 8;

    const int fr = l & 15;
    const int kq = (l >> 4) * 8;

    floatx4 acc[4][4] = {};

    for (int kt = 0; kt < 1024; kt += 32) {
        __syncthreads();
        g2l16(ga, la);
        g2l16(ga + (long long)64 * 4096, la + 64 * 32);
        g2l16(gb, lb);
        g2l16(gb + (long long)64 * 4096, lb + 64 * 32);
        ga += 32; gb += 32;
        __syncthreads();

        bf16x8 af[4], bfr[4];
#pragma unroll
        for (int i = 0; i < 4; ++i) {
            af[i]  = *(const bf16x8*)(As + (wm + i * 16 + fr) * 32 + kq);
            bfr[i] = *(const bf16x8*)(Bs + (wn + i * 16 + fr) * 32 + kq);
        }
#pragma unroll
        for (int i = 0; i < 4; ++i)
#pragma unroll
            for (int j = 0; j < 4; ++j)
                acc[i][j] = __builtin_amdgcn_mfma_f32_16x16x32_bf16(
                    af[i], bfr[j], acc[i][j], 0, 0, 0);
    }

    const int col = l & 15;
    const int rbase = (l >> 4) * 4;
    float* Pb = P + ((long long)z * 16 + blockIdx.y * 4 + blockIdx.x) * 16384;
#pragma unroll
    for (int i = 0; i < 4; ++i)
#pragma unroll
        for (int j = 0; j < 4; ++j)
#pragma unroll
            for (int r = 0; r < 4; ++r)
                Pb[(wm + i * 16 + rbase + r) * 128 + wn + j * 16 + col] =
                    acc[i][j][r];
}

// Sum the 4 split-K partials -> bf16 ctxT[b, e, d] (row-major 512x512/batch).
__global__ __launch_bounds__(256) void ctx_reduce(const float* __restrict__ P,
                                                  unsigned short* __restrict__ Ct)
{
    long long f = (long long)blockIdx.x * 256 + threadIdx.x;
    long long base = f * 4;
    int tile = (int)(base >> 14);          // (b, mt, nt)
    int lo = (int)(base & 16383);
    int b = tile >> 4;
    int mt = (tile >> 2) & 3;
    int nt = tile & 3;
    float4 s = {0.f, 0.f, 0.f, 0.f};
#pragma unroll
    for (int sp = 0; sp < 4; ++sp) {
        float4 v = *(const float4*)(P + ((long long)(b * 4 + sp) * 16 + mt * 4 + nt) * 16384 + lo);
        s.x += v.x; s.y += v.y; s.z += v.z; s.w += v.w;
    }
    int le = lo >> 7;
    int ld = lo & 127;
    us4 o = { f2b(s.x), f2b(s.y), f2b(s.z), f2b(s.w) };
    *(us4*)(Ct + (long long)b * 262144 + (mt * 128 + le) * 512 + nt * 128 + ld) = o;
}

// ---------------------------------------------------------------------------
// conversions
// ---------------------------------------------------------------------------
__global__ __launch_bounds__(256) void f32_to_bf16_k(const float* __restrict__ in,
                                                     unsigned short* __restrict__ out)
{
    long long i = ((long long)blockIdx.x * 256 + threadIdx.x) * 4;
    float4 v = *(const float4*)(in + i);
    us4 o = { f2b(v.x), f2b(v.y), f2b(v.z), f2b(v.w) };
    *(us4*)(out + i) = o;
}

struct WPtrs { const float* in[5]; unsigned short* out[5]; };
__global__ __launch_bounds__(256) void conv_weights(WPtrs p)
{
    int which = blockIdx.y;
    long long i = ((long long)blockIdx.x * 256 + threadIdx.x) * 4;
    float4 v = *(const float4*)(p.in[which] + i);
    us4 o = { f2b(v.x), f2b(v.y), f2b(v.z), f2b(v.w) };
    *(us4*)(p.out[which] + i) = o;
}

// ---------------------------------------------------------------------------
// softmax over rows of length 512, in place, times `scale` (q path)
// ---------------------------------------------------------------------------
__global__ __launch_bounds__(256) void softmax_row512(unsigned short* __restrict__ q,
                                                      float scale)
{
    __shared__ float red[8];
    unsigned short* p = q + (long long)blockIdx.x * 512;
    int t = threadIdx.x;
    uint v = *(const uint*)(p + 2 * t);
    float a = b2f((unsigned short)(v & 0xffff));
    float b = b2f((unsigned short)(v >> 16));
    float mx = wave_max(fmaxf(a, b));
    int w = t >> 6;
    if ((t & 63) == 0) red[w] = mx;
    __syncthreads();
    mx = fmaxf(fmaxf(red[0], red[1]), fmaxf(red[2], red[3]));
    float ea = __expf(a - mx), eb = __expf(b - mx);
    float s = wave_sum(ea + eb);
    if ((t & 63) == 0) red[4 + w] = s;
    __syncthreads();
    s = red[4] + red[5] + red[6] + red[7];
    float inv = scale / s;
    uint o = (uint)f2b(ea * inv) | ((uint)f2b(eb * inv) << 16);
    *(uint*)(p + 2 * t) = o;
}

// ---------------------------------------------------------------------------
// softmax over rows of length 4096, in place (k path, rows = (b,c) of kT)
// ---------------------------------------------------------------------------
__global__ __launch_bounds__(256) void softmax_row4096(unsigned short* __restrict__ kk)
{
    __shared__ float red[8];
    unsigned short* p = kk + (long long)blockIdx.x * 4096;
    int t = threadIdx.x;
    uint4 v0 = *(const uint4*)(p + 16 * t);
    uint4 v1 = *(const uint4*)(p + 16 * t + 8);
    uint u[8] = { v0.x, v0.y, v0.z, v0.w, v1.x, v1.y, v1.z, v1.w };
    float f[16];
#pragma unroll
    for (int i = 0; i < 8; ++i) {
        f[2 * i]     = b2f((unsigned short)(u[i] & 0xffff));
        f[2 * i + 1] = b2f((unsigned short)(u[i] >> 16));
    }
    float mx = f[0];
#pragma unroll
    for (int i = 1; i < 16; ++i) mx = fmaxf(mx, f[i]);
    mx = wave_max(mx);
    int w = t >> 6;
    if ((t & 63) == 0) red[w] = mx;
    __syncthreads();
    mx = fmaxf(fmaxf(red[0], red[1]), fmaxf(red[2], red[3]));
    float s = 0.f;
#pragma unroll
    for (int i = 0; i < 16; ++i) { f[i] = __expf(f[i] - mx); s += f[i]; }
    s = wave_sum(s);
    if ((t & 63) == 0) red[4 + w] = s;
    __syncthreads();
    s = red[4] + red[5] + red[6] + red[7];
    float inv = 1.f / s;
    uint o[8];
#pragma unroll
    for (int i = 0; i < 8; ++i)
        o[i] = (uint)f2b(f[2 * i] * inv) | ((uint)f2b(f[2 * i + 1] * inv) << 16);
    *(uint4*)(p + 16 * t)     = make_uint4(o[0], o[1], o[2], o[3]);
    *(uint4*)(p + 16 * t + 8) = make_uint4(o[4], o[5], o[6], o[7]);
}

// ---------------------------------------------------------------------------
extern "C" void kernel_launch(void* const* d_in, const int* in_sizes, int n_in,
                              void* d_out, int out_size, void* d_ws, size_t ws_size,
                              hipStream_t stream)
{
    (void)in_sizes; (void)n_in; (void)out_size; (void)ws_size;
    const float* x  = (const float*)d_in[0];
    const float* Wq = (const float*)d_in[1];
    const float* Wk = (const float*)d_in[2];
    const float* Wv = (const float*)d_in[3];
    const float* W1 = (const float*)d_in[4];
    const float* W2 = (const float*)d_in[5];
    float* out = (float*)d_out;

    const int Bn = 8, N = 4096, C = 512;
    const long long M  = (long long)Bn * N;   // 32768
    const long long XE = M * C;               // 16,777,216 elements

    char* ws = (char*)d_ws;
    size_t off = 0;
    auto carve = [&](size_t bytes) -> void* {
        void* p = ws + off;
        off += (bytes + 255) & ~(size_t)255;
        return p;
    };

    unsigned short* xb   = (unsigned short*)carve(XE * 2);
    unsigned short* wcat = (unsigned short*)carve((size_t)3 * C * C * 2); // [Wq;Wk;Wv]
    unsigned short* w1b  = (unsigned short*)carve((size_t)C * C * 2);
    unsigned short* w2b  = (unsigned short*)carve((size_t)C * C * 2);
    unsigned short* q    = (unsigned short*)carve(XE * 2);
    unsigned short* kT   = (unsigned short*)carve(XE * 2);   // [b, c, n]
    unsigned short* vT   = (unsigned short*)carve(XE * 2);   // [b, c, n]
    unsigned short* ctxT = (unsigned short*)carve((size_t)Bn * C * C * 2); // [b, e, d]
    unsigned short* xr = kT;       // alias: kT dead after ctx gemm
    unsigned short* h  = vT;       // alias: vT dead after ctx gemm
    float* P = (float*)d_out;      // split-K partials: d_out is scratch until
                                   // the final gemm overwrites all of it

    // dtype conversions
    f32_to_bf16_k<<<dim3((unsigned)(XE / 1024)), dim3(256), 0, stream>>>(x, xb);
    WPtrs wp = { { Wq, Wk, Wv, W1, W2 },
                 { wcat, wcat + C * C, wcat + 2 * C * C, w1b, w2b } };
    conv_weights<<<dim3((C * C) / 1024, 5), dim3(256), 0, stream>>>(wp);

    // fused q/k/v: one pass over xb, B = wcat (1536x512)
    gemm128<4><<<dim3(12, M / 128, 1), 256, 0, stream>>>(
        xb, wcat, q, nullptr, kT, vT, C, C, C, C, 0, 0, 0, 0);

    // softmaxes (in place)
    softmax_row512<<<dim3((unsigned)M), 256, 0, stream>>>(q, 0.044194173824159216f);
    softmax_row4096<<<dim3(Bn * C), 256, 0, stream>>>(kT);

    // ctxT[b,e,d] = sum_n vT[b,e,n] * kT[b,d,n]  (split-K=4 + reduce)
    ctx_gemm_sk<<<dim3(4, 4, 32), 256, 0, stream>>>(vT, kT, P);
    ctx_reduce<<<dim3(2048), 256, 0, stream>>>(P, ctxT);

    // xr[b,n,e] = sum_d q[b,n,d] * ctxT[b,e,d] + x[b,n,e]
    gemm128<2><<<dim3(4, N / 128, Bn), 256, 0, stream>>>(
        q, ctxT, xr, xb, nullptr, nullptr, C, C, C, C,
        (long long)N * C, (long long)C * C, (long long)N * C, (long long)N * C);

    // h = xr @ W1.T
    gemm128<0><<<dim3(4, M / 128, 1), 256, 0, stream>>>(
        xr, w1b, h, nullptr, nullptr, nullptr, C, C, C, C, 0, 0, 0, 0);

    // out = h @ W2.T + xr   (fp32 output)
    gemm128<3><<<dim3(4, M / 128, 1), 256, 0, stream>>>(
        h, w2b, out, xr, nullptr, nullptr, C, C, C, C, 0, 0, 0, 0);
}

// Round 4
// 344.212 us; speedup vs baseline: 1.2506x; 1.1091x over previous
//
#include <hip/hip_runtime.h>

typedef unsigned int uint;
typedef __bf16 bf16_t;
typedef bf16_t bf16x8 __attribute__((ext_vector_type(8)));
typedef float floatx4 __attribute__((ext_vector_type(4)));

struct __align__(8) us4 { unsigned short x, y, z, w; };

__device__ __forceinline__ unsigned short f2b(float f) {
    unsigned u = __float_as_uint(f);
    u = u + 0x7FFFu + ((u >> 16) & 1u);   // RNE
    return (unsigned short)(u >> 16);
}
__device__ __forceinline__ float b2f(unsigned short h) {
    return __uint_as_float(((unsigned)h) << 16);
}

// async global->LDS, 16B per lane; LDS dest is wave-uniform base + lane*16
__device__ __forceinline__ void g2l16(const void* g, void* l) {
    __builtin_amdgcn_global_load_lds((__attribute__((address_space(1))) void*)g,
                                     (__attribute__((address_space(3))) void*)l,
                                     16, 0, 0);
}

__device__ __forceinline__ float wave_max(float v) {
#pragma unroll
    for (int m = 32; m > 0; m >>= 1) v = fmaxf(v, __shfl_xor(v, m));
    return v;
}
__device__ __forceinline__ float wave_sum(float v) {
#pragma unroll
    for (int m = 32; m > 0; m >>= 1) v += __shfl_xor(v, m);
    return v;
}

// ---------------------------------------------------------------------------
// gemm128s: O[m,n] = sum_k A[m,k] * B[n,k] (row-major, K inner), 128x128 tile,
// BK=32, 256 threads (4 waves 2x2). 1-D grid with explicit XCD swizzle:
//   xcd = id & 7; g = id >> 3; nt = g % NT; ms = (g / NT) * 8 + xcd
// -> all NT n-tiles of an A-stripe run consecutively on ONE XCD, so the
// 128 KB A-stripe is fetched from HBM once chip-wide (XCD L2 = 4 MB).
// BMS=true decodes ms as (mt*8 + b): batch b pinned to XCD b -> each XCD
// touches only its own B (ctxT[b], 0.5 MB).
// MODE 0: bf16 store O[m*ldo+n]
// MODE 2: bf16 store of (acc + R[m*ldo+n])
// MODE 3: f32  store of (acc + R[m*ldo+n])
// MODE 4: fused qkv. B = concat(Wq,Wk,Wv) [1536x512]. n<512 -> plain bf16
//         store to O (=q). 512..1023 -> transposed store to O2 (=kT[b,c,n]).
//         >=1024 -> transposed store to O3 (=vT[b,c,n]).  (4096 rows/batch)
// ---------------------------------------------------------------------------
template <int MODE, int NT, bool BMS>
__global__ __launch_bounds__(256, 4) void gemm128s(
    const unsigned short* __restrict__ A, const unsigned short* __restrict__ B,
    void* __restrict__ O, const unsigned short* __restrict__ R,
    unsigned short* __restrict__ O2, unsigned short* __restrict__ O3,
    int K, int lda, int ldb, int ldo, long long sB)
{
    __shared__ __attribute__((aligned(16))) unsigned short As[128 * 32];
    __shared__ __attribute__((aligned(16))) unsigned short Bs[128 * 32];

    const uint id = blockIdx.x;
    const uint xcd = id & 7;
    const uint g = id >> 3;
    const uint nt = g % NT;
    const uint mg = g / NT;
    const uint ms = mg * 8 + xcd;

    int bb, arow0;
    if constexpr (BMS) { bb = ms & 7; arow0 = bb * 4096 + (int)(ms >> 3) * 128; }
    else               { bb = 0;      arow0 = (int)ms * 128; }
    const int n0 = (int)nt * 128;

    const unsigned short* Bb = B + (long long)bb * sB;
    const int tid = threadIdx.x;
    const int l = tid & 63;
    const int w = tid >> 6;
    const int wm = (w >> 1) * 64;
    const int wn = (w & 1) * 64;

    // staging: thread t covers row (t>>2), 16B chunk (t&3) of the 64B k-row
    const int srow = tid >> 2;
    const int scol = (tid & 3) * 8;
    const unsigned short* ga = A + (long long)(arow0 + srow) * lda + scol;
    const unsigned short* gb = Bb + (long long)(n0 + srow) * ldb + scol;
    unsigned short* la = As + tid * 8;
    unsigned short* lb = Bs + tid * 8;

    const int fr = l & 15;
    const int kq = (l >> 4) * 8;

    floatx4 acc[4][4] = {};

    for (int kt = 0; kt < K; kt += 32) {
        __syncthreads();                       // previous tile fully consumed
        g2l16(ga, la);
        g2l16(ga + (long long)64 * lda, la + 64 * 32);
        g2l16(gb, lb);
        g2l16(gb + (long long)64 * ldb, lb + 64 * 32);
        ga += 32; gb += 32;
        __syncthreads();                       // staging complete

        bf16x8 af[4], bfr[4];
#pragma unroll
        for (int i = 0; i < 4; ++i) {
            af[i]  = *(const bf16x8*)(As + (wm + i * 16 + fr) * 32 + kq);
            bfr[i] = *(const bf16x8*)(Bs + (wn + i * 16 + fr) * 32 + kq);
        }
#pragma unroll
        for (int i = 0; i < 4; ++i)
#pragma unroll
            for (int j = 0; j < 4; ++j)
                acc[i][j] = __builtin_amdgcn_mfma_f32_16x16x32_bf16(
                    af[i], bfr[j], acc[i][j], 0, 0, 0);
    }

    // C/D layout (verified m89/m91): col = lane&15, row = (lane>>4)*4 + reg
    const int col = l & 15;
    const int rbase = (l >> 4) * 4;

    if constexpr (MODE == 4) {
        if (n0 < 512) {
            unsigned short* Oq = (unsigned short*)O;
#pragma unroll
            for (int i = 0; i < 4; ++i)
#pragma unroll
                for (int j = 0; j < 4; ++j) {
                    int gn = n0 + wn + j * 16 + col;
                    int gmb = arow0 + wm + i * 16 + rbase;
#pragma unroll
                    for (int r = 0; r < 4; ++r)
                        Oq[(long long)(gmb + r) * 512 + gn] = f2b(acc[i][j][r]);
                }
        } else {
            unsigned short* T = (n0 < 1024) ? O2 : O3;
            const int nbase = (n0 < 1024) ? 512 : 1024;
            const int b = arow0 >> 12;          // row / 4096
            const int mq0 = arow0 & 4095;
#pragma unroll
            for (int i = 0; i < 4; ++i)
#pragma unroll
                for (int j = 0; j < 4; ++j) {
                    int gn = n0 + wn + j * 16 + col - nbase;
                    int mq = mq0 + wm + i * 16 + rbase;
                    us4 pk = { f2b(acc[i][j][0]), f2b(acc[i][j][1]),
                               f2b(acc[i][j][2]), f2b(acc[i][j][3]) };
                    *(us4*)(T + ((long long)b * 512 + gn) * 4096 + mq) = pk;
                }
        }
    } else {
#pragma unroll
        for (int i = 0; i < 4; ++i)
#pragma unroll
            for (int j = 0; j < 4; ++j) {
                int gn = n0 + wn + j * 16 + col;
                int gmb = arow0 + wm + i * 16 + rbase;
#pragma unroll
                for (int r = 0; r < 4; ++r) {
                    long long idx = (long long)(gmb + r) * ldo + gn;
                    float v = acc[i][j][r];
                    if constexpr (MODE == 0) {
                        ((unsigned short*)O)[idx] = f2b(v);
                    } else if constexpr (MODE == 2) {
                        ((unsigned short*)O)[idx] = f2b(v + b2f(R[idx]));
                    } else {
                        ((float*)O)[idx] = v + b2f(R[idx]);
                    }
                }
            }
    }
}

// ---------------------------------------------------------------------------
// ctx split-K gemm: partial of ctxT[b,e,d] = sum_n vT[b,e,n]*kT[b,d,n].
// 128x128 tile, BK=32, split-K=4 (K=1024 per block). 512 blocks, 1-D grid:
//   xcd = id&7; g = id>>3; tile = g&15; z = (g>>4)*8 + xcd
// -> each (b,s) K-slice (2 MB working set: 0.5 MB vT + 0.5 MB kT per split...
//    4x128KB A-stripes + 4x128KB B-stripes = 1 MB) pinned to ONE XCD; all
// tile re-reads served from that XCD's L2 -> fetch = compulsory 64 MB.
// Partials fp32 to scratch (d_out).
// ---------------------------------------------------------------------------
__global__ __launch_bounds__(256, 4) void ctx_gemm_sk(
    const unsigned short* __restrict__ V, const unsigned short* __restrict__ Kt,
    float* __restrict__ P)
{
    __shared__ __attribute__((aligned(16))) unsigned short As[128 * 32];
    __shared__ __attribute__((aligned(16))) unsigned short Bs[128 * 32];

    const uint id = blockIdx.x;          // 0..511
    const uint xcd = id & 7;
    const uint g = id >> 3;              // 0..63
    const uint sub = g & 15;             // tile within (b,s)
    const int z = (int)(g >> 4) * 8 + (int)xcd;   // 0..31 = b*4+s
    const int b = z >> 2;
    const int s = z & 3;
    const int m0 = (int)(sub >> 2) * 128;
    const int n0 = (int)(sub & 3) * 128;

    const unsigned short* Ab = V  + (long long)b * 512 * 4096 + s * 1024;
    const unsigned short* Bb = Kt + (long long)b * 512 * 4096 + s * 1024;

    const int tid = threadIdx.x;
    const int l = tid & 63;
    const int w = tid >> 6;
    const int wm = (w >> 1) * 64;
    const int wn = (w & 1) * 64;

    const int srow = tid >> 2;
    const int scol = (tid & 3) * 8;
    const unsigned short* ga = Ab + (long long)(m0 + srow) * 4096 + scol;
    const unsigned short* gb = Bb + (long long)(n0 + srow) * 4096 + scol;
    unsigned short* la = As + tid * 8;
    unsigned short* lb = Bs + tid * 8;

    const int fr = l & 15;
    const int kq = (l >> 4) * 8;

    floatx4 acc[4][4] = {};

    for (int kt = 0; kt < 1024; kt += 32) {
        __syncthreads();
        g2l16(ga, la);
        g2l16(ga + (long long)64 * 4096, la + 64 * 32);
        g2l16(gb, lb);
        g2l16(gb + (long long)64 * 4096, lb + 64 * 32);
        ga += 32; gb += 32;
        __syncthreads();

        bf16x8 af[4], bfr[4];
#pragma unroll
        for (int i = 0; i < 4; ++i) {
            af[i]  = *(const bf16x8*)(As + (wm + i * 16 + fr) * 32 + kq);
            bfr[i] = *(const bf16x8*)(Bs + (wn + i * 16 + fr) * 32 + kq);
        }
#pragma unroll
        for (int i = 0; i < 4; ++i)
#pragma unroll
            for (int j = 0; j < 4; ++j)
                acc[i][j] = __builtin_amdgcn_mfma_f32_16x16x32_bf16(
                    af[i], bfr[j], acc[i][j], 0, 0, 0);
    }

    const int col = l & 15;
    const int rbase = (l >> 4) * 4;
    float* Pb = P + ((long long)z * 16 + (sub >> 2) * 4 + (sub & 3)) * 16384;
#pragma unroll
    for (int i = 0; i < 4; ++i)
#pragma unroll
        for (int j = 0; j < 4; ++j)
#pragma unroll
            for (int r = 0; r < 4; ++r)
                Pb[(wm + i * 16 + rbase + r) * 128 + wn + j * 16 + col] =
                    acc[i][j][r];
}

// Sum the 4 split-K partials -> bf16 ctxT[b, e, d] (row-major 512x512/batch).
__global__ __launch_bounds__(256) void ctx_reduce(const float* __restrict__ P,
                                                  unsigned short* __restrict__ Ct)
{
    long long f = (long long)blockIdx.x * 256 + threadIdx.x;
    long long base = f * 4;
    int tile = (int)(base >> 14);          // (b, mt, nt)
    int lo = (int)(base & 16383);
    int b = tile >> 4;
    int mt = (tile >> 2) & 3;
    int nt = tile & 3;
    float4 s = {0.f, 0.f, 0.f, 0.f};
#pragma unroll
    for (int sp = 0; sp < 4; ++sp) {
        float4 v = *(const float4*)(P + ((long long)(b * 4 + sp) * 16 + mt * 4 + nt) * 16384 + lo);
        s.x += v.x; s.y += v.y; s.z += v.z; s.w += v.w;
    }
    int le = lo >> 7;
    int ld = lo & 127;
    us4 o = { f2b(s.x), f2b(s.y), f2b(s.z), f2b(s.w) };
    *(us4*)(Ct + (long long)b * 262144 + (mt * 128 + le) * 512 + nt * 128 + ld) = o;
}

// ---------------------------------------------------------------------------
// conversions
// ---------------------------------------------------------------------------
__global__ __launch_bounds__(256) void f32_to_bf16_k(const float* __restrict__ in,
                                                     unsigned short* __restrict__ out)
{
    long long i = ((long long)blockIdx.x * 256 + threadIdx.x) * 4;
    float4 v = *(const float4*)(in + i);
    us4 o = { f2b(v.x), f2b(v.y), f2b(v.z), f2b(v.w) };
    *(us4*)(out + i) = o;
}

struct WPtrs { const float* in[5]; unsigned short* out[5]; };
__global__ __launch_bounds__(256) void conv_weights(WPtrs p)
{
    int which = blockIdx.y;
    long long i = ((long long)blockIdx.x * 256 + threadIdx.x) * 4;
    float4 v = *(const float4*)(p.in[which] + i);
    us4 o = { f2b(v.x), f2b(v.y), f2b(v.z), f2b(v.w) };
    *(us4*)(p.out[which] + i) = o;
}

// ---------------------------------------------------------------------------
// softmax over rows of length 512, in place, times `scale` (q path)
// ---------------------------------------------------------------------------
__global__ __launch_bounds__(256) void softmax_row512(unsigned short* __restrict__ q,
                                                      float scale)
{
    __shared__ float red[8];
    unsigned short* p = q + (long long)blockIdx.x * 512;
    int t = threadIdx.x;
    uint v = *(const uint*)(p + 2 * t);
    float a = b2f((unsigned short)(v & 0xffff));
    float b = b2f((unsigned short)(v >> 16));
    float mx = wave_max(fmaxf(a, b));
    int w = t >> 6;
    if ((t & 63) == 0) red[w] = mx;
    __syncthreads();
    mx = fmaxf(fmaxf(red[0], red[1]), fmaxf(red[2], red[3]));
    float ea = __expf(a - mx), eb = __expf(b - mx);
    float s = wave_sum(ea + eb);
    if ((t & 63) == 0) red[4 + w] = s;
    __syncthreads();
    s = red[4] + red[5] + red[6] + red[7];
    float inv = scale / s;
    uint o = (uint)f2b(ea * inv) | ((uint)f2b(eb * inv) << 16);
    *(uint*)(p + 2 * t) = o;
}

// ---------------------------------------------------------------------------
// softmax over rows of length 4096, in place (k path, rows = (b,c) of kT)
// ---------------------------------------------------------------------------
__global__ __launch_bounds__(256) void softmax_row4096(unsigned short* __restrict__ kk)
{
    __shared__ float red[8];
    unsigned short* p = kk + (long long)blockIdx.x * 4096;
    int t = threadIdx.x;
    uint4 v0 = *(const uint4*)(p + 16 * t);
    uint4 v1 = *(const uint4*)(p + 16 * t + 8);
    uint u[8] = { v0.x, v0.y, v0.z, v0.w, v1.x, v1.y, v1.z, v1.w };
    float f[16];
#pragma unroll
    for (int i = 0; i < 8; ++i) {
        f[2 * i]     = b2f((unsigned short)(u[i] & 0xffff));
        f[2 * i + 1] = b2f((unsigned short)(u[i] >> 16));
    }
    float mx = f[0];
#pragma unroll
    for (int i = 1; i < 16; ++i) mx = fmaxf(mx, f[i]);
    mx = wave_max(mx);
    int w = t >> 6;
    if ((t & 63) == 0) red[w] = mx;
    __syncthreads();
    mx = fmaxf(fmaxf(red[0], red[1]), fmaxf(red[2], red[3]));
    float s = 0.f;
#pragma unroll
    for (int i = 0; i < 16; ++i) { f[i] = __expf(f[i] - mx); s += f[i]; }
    s = wave_sum(s);
    if ((t & 63) == 0) red[4 + w] = s;
    __syncthreads();
    s = red[4] + red[5] + red[6] + red[7];
    float inv = 1.f / s;
    uint o[8];
#pragma unroll
    for (int i = 0; i < 8; ++i)
        o[i] = (uint)f2b(f[2 * i] * inv) | ((uint)f2b(f[2 * i + 1] * inv) << 16);
    *(uint4*)(p + 16 * t)     = make_uint4(o[0], o[1], o[2], o[3]);
    *(uint4*)(p + 16 * t + 8) = make_uint4(o[4], o[5], o[6], o[7]);
}

// ---------------------------------------------------------------------------
extern "C" void kernel_launch(void* const* d_in, const int* in_sizes, int n_in,
                              void* d_out, int out_size, void* d_ws, size_t ws_size,
                              hipStream_t stream)
{
    (void)in_sizes; (void)n_in; (void)out_size; (void)ws_size;
    const float* x  = (const float*)d_in[0];
    const float* Wq = (const float*)d_in[1];
    const float* Wk = (const float*)d_in[2];
    const float* Wv = (const float*)d_in[3];
    const float* W1 = (const float*)d_in[4];
    const float* W2 = (const float*)d_in[5];
    float* out = (float*)d_out;

    const int Bn = 8, N = 4096, C = 512;
    const long long M  = (long long)Bn * N;   // 32768
    const long long XE = M * C;               // 16,777,216 elements

    char* ws = (char*)d_ws;
    size_t off = 0;
    auto carve = [&](size_t bytes) -> void* {
        void* p = ws + off;
        off += (bytes + 255) & ~(size_t)255;
        return p;
    };

    unsigned short* xb   = (unsigned short*)carve(XE * 2);
    unsigned short* wcat = (unsigned short*)carve((size_t)3 * C * C * 2); // [Wq;Wk;Wv]
    unsigned short* w1b  = (unsigned short*)carve((size_t)C * C * 2);
    unsigned short* w2b  = (unsigned short*)carve((size_t)C * C * 2);
    unsigned short* q    = (unsigned short*)carve(XE * 2);
    unsigned short* kT   = (unsigned short*)carve(XE * 2);   // [b, c, n]
    unsigned short* vT   = (unsigned short*)carve(XE * 2);   // [b, c, n]
    unsigned short* ctxT = (unsigned short*)carve((size_t)Bn * C * C * 2); // [b, e, d]
    unsigned short* xr = kT;       // alias: kT dead after ctx gemm
    unsigned short* h  = vT;       // alias: vT dead after ctx gemm
    float* P = (float*)d_out;      // split-K partials: d_out is scratch until
                                   // the final gemm overwrites all of it

    // dtype conversions
    f32_to_bf16_k<<<dim3((unsigned)(XE / 1024)), dim3(256), 0, stream>>>(x, xb);
    WPtrs wp = { { Wq, Wk, Wv, W1, W2 },
                 { wcat, wcat + C * C, wcat + 2 * C * C, w1b, w2b } };
    conv_weights<<<dim3((C * C) / 1024, 5), dim3(256), 0, stream>>>(wp);

    // fused q/k/v: one pass over xb, B = wcat (1536x512). 256 m-stripes x 12.
    gemm128s<4, 12, false><<<dim3(3072), 256, 0, stream>>>(
        xb, wcat, q, nullptr, kT, vT, C, C, C, C, 0);

    // softmaxes (in place)
    softmax_row512<<<dim3((unsigned)M), 256, 0, stream>>>(q, 0.044194173824159216f);
    softmax_row4096<<<dim3(Bn * C), 256, 0, stream>>>(kT);

    // ctxT[b,e,d] = sum_n vT[b,e,n] * kT[b,d,n]  (split-K=4 + reduce)
    ctx_gemm_sk<<<dim3(512), 256, 0, stream>>>(vT, kT, P);
    ctx_reduce<<<dim3(2048), 256, 0, stream>>>(P, ctxT);

    // xr[b,n,e] = sum_d q[b,n,d] * ctxT[b,e,d] + x[b,n,e]   (batch-pinned)
    gemm128s<2, 4, true><<<dim3(1024), 256, 0, stream>>>(
        q, ctxT, xr, xb, nullptr, nullptr, C, C, C, C, (long long)C * C);

    // h = xr @ W1.T
    gemm128s<0, 4, false><<<dim3(1024), 256, 0, stream>>>(
        xr, w1b, h, nullptr, nullptr, nullptr, C, C, C, C, 0);

    // out = h @ W2.T + xr   (fp32 output)
    gemm128s<3, 4, false><<<dim3(1024), 256, 0, stream>>>(
        h, w2b, out, xr, nullptr, nullptr, C, C, C, C, 0);
}

// Round 5
// 311.166 us; speedup vs baseline: 1.3835x; 1.1062x over previous
//
#include <hip/hip_runtime.h>

typedef unsigned int uint;
typedef __bf16 bf16_t;
typedef bf16_t bf16x8 __attribute__((ext_vector_type(8)));
typedef float floatx4 __attribute__((ext_vector_type(4)));

struct __align__(8) us4 { unsigned short x, y, z, w; };

__device__ __forceinline__ unsigned short f2b(float f) {
    unsigned u = __float_as_uint(f);
    u = u + 0x7FFFu + ((u >> 16) & 1u);   // RNE
    return (unsigned short)(u >> 16);
}
__device__ __forceinline__ float b2f(unsigned short h) {
    return __uint_as_float(((unsigned)h) << 16);
}

// async global->LDS, 16B per lane; LDS dest is wave-uniform base + lane*16
__device__ __forceinline__ void g2l16(const void* g, void* l) {
    __builtin_amdgcn_global_load_lds((__attribute__((address_space(1))) void*)g,
                                     (__attribute__((address_space(3))) void*)l,
                                     16, 0, 0);
}

// ---------------------------------------------------------------------------
// gemm64: O[m,n] = sum_k A[m,k]*B[n,k] (row-major, K inner). 128x128 tile,
// BK=64 (halves the vmcnt(0)+barrier drains vs BK=32; LDS 32 KB/block keeps
// 4 blocks/CU). 256 threads, 4 waves 2x2, wave 64x64 = 4x4 MFMA frags,
// fragments consumed in two K-halves to bound live registers.
// 1-D grid, explicit XCD swizzle (round-robin id%8 = XCD):
//   xcd=id&7; g=id>>3; nt=g%NT; ms=(g/NT)*8+xcd  -> one A-stripe per XCD.
// BMS: ms decodes as (mt*8 + batch) -> batch pinned to XCD.
// MODE 0: bf16 store
// MODE 3: f32 store of acc + R (residual)
// MODE 5: bf16 store of acc*(scale/Sn[row]) + R   (attn: fused q-softmax norm)
// MODE 4: fused qkv, B=concat(Wq,Wk,Wv)[1536x512]:
//   n<512    : store exp(acc) -> O (=eq), atomicAdd row sums into Sq[m]
//   512..1023: store exp(acc) transposed -> O2 (=ekT[b,d,n]), atomicAdd
//              column sums into Sk[b*512+d]
//   >=1024   : store acc transposed -> O3 (=vT[b,e,n])
// ---------------------------------------------------------------------------
template <int MODE, int NT, bool BMS>
__global__ __launch_bounds__(256, 4) void gemm64(
    const unsigned short* __restrict__ A, const unsigned short* __restrict__ B,
    void* __restrict__ O, const unsigned short* __restrict__ R,
    unsigned short* __restrict__ O2, unsigned short* __restrict__ O3,
    float* __restrict__ Sq, float* __restrict__ Sk,
    const float* __restrict__ Sn,
    int K, int lda, int ldb, int ldo, long long sB, float scale)
{
    __shared__ __attribute__((aligned(16))) unsigned short As[128 * 64];
    __shared__ __attribute__((aligned(16))) unsigned short Bs[128 * 64];

    const uint id = blockIdx.x;
    const uint xcd = id & 7;
    const uint g = id >> 3;
    const uint nt = g % NT;
    const uint mg = g / NT;
    const uint ms = mg * 8 + xcd;

    int bb, arow0;
    if constexpr (BMS) { bb = ms & 7; arow0 = bb * 4096 + (int)(ms >> 3) * 128; }
    else               { bb = 0;      arow0 = (int)ms * 128; }
    const int n0 = (int)nt * 128;

    const unsigned short* Bb = B + (long long)bb * sB;
    const int tid = threadIdx.x;
    const int l = tid & 63;
    const int w = tid >> 6;
    const int wm = (w >> 1) * 64;
    const int wn = (w & 1) * 64;

    // staging: call c covers rows c*32 + (t>>3), 16B chunk (t&7) of 128B row
    const int srow = tid >> 3;
    const int scol = (tid & 7) * 8;
    const unsigned short* ga = A + (long long)(arow0 + srow) * lda + scol;
    const unsigned short* gb = Bb + (long long)(n0 + srow) * ldb + scol;
    unsigned short* la = As + tid * 8;
    unsigned short* lb = Bs + tid * 8;

    const int fr = l & 15;
    const int kq = (l >> 4) * 8;

    floatx4 acc[4][4] = {};

    for (int kt = 0; kt < K; kt += 64) {
        __syncthreads();                       // previous tile fully consumed
#pragma unroll
        for (int c = 0; c < 4; ++c) {
            g2l16(ga + (long long)(c * 32) * lda, la + c * 2048);
            g2l16(gb + (long long)(c * 32) * ldb, lb + c * 2048);
        }
        ga += 64; gb += 64;
        __syncthreads();                       // staging complete

#pragma unroll
        for (int h = 0; h < 2; ++h) {
            bf16x8 af[4], bfr[4];
#pragma unroll
            for (int i = 0; i < 4; ++i) {
                af[i]  = *(const bf16x8*)(As + (wm + i * 16 + fr) * 64 + kq + 32 * h);
                bfr[i] = *(const bf16x8*)(Bs + (wn + i * 16 + fr) * 64 + kq + 32 * h);
            }
#pragma unroll
            for (int i = 0; i < 4; ++i)
#pragma unroll
                for (int j = 0; j < 4; ++j)
                    acc[i][j] = __builtin_amdgcn_mfma_f32_16x16x32_bf16(
                        af[i], bfr[j], acc[i][j], 0, 0, 0);
        }
    }

    // C/D layout (verified m89/m91): col = lane&15, row = (lane>>4)*4 + reg
    const int col = l & 15;
    const int rbase = (l >> 4) * 4;

    if constexpr (MODE == 4) {
        if (n0 < 512) {
            // q branch: store exp, row-sum atomics
            unsigned short* Oq = (unsigned short*)O;
            float rs[4][4];
#pragma unroll
            for (int i = 0; i < 4; ++i)
#pragma unroll
                for (int r = 0; r < 4; ++r) rs[i][r] = 0.f;
#pragma unroll
            for (int i = 0; i < 4; ++i)
#pragma unroll
                for (int j = 0; j < 4; ++j) {
                    int gn = n0 + wn + j * 16 + col;
                    int gmb = arow0 + wm + i * 16 + rbase;
#pragma unroll
                    for (int r = 0; r < 4; ++r) {
                        float e = __expf(acc[i][j][r]);
                        rs[i][r] += e;
                        Oq[(long long)(gmb + r) * 512 + gn] = f2b(e);
                    }
                }
#pragma unroll
            for (int i = 0; i < 4; ++i)
#pragma unroll
                for (int r = 0; r < 4; ++r) {
                    float v = rs[i][r];
                    v += __shfl_xor(v, 1);
                    v += __shfl_xor(v, 2);
                    v += __shfl_xor(v, 4);
                    v += __shfl_xor(v, 8);
                    if ((l & 15) == 0)
                        atomicAdd(&Sq[arow0 + wm + i * 16 + rbase + r], v);
                }
        } else if (n0 < 1024) {
            // k branch: store exp transposed, column-sum atomics
            const int b = arow0 >> 12;
            const int mq0 = arow0 & 4095;
            float cs[4] = {0.f, 0.f, 0.f, 0.f};
#pragma unroll
            for (int i = 0; i < 4; ++i)
#pragma unroll
                for (int j = 0; j < 4; ++j) {
                    int d = n0 + wn + j * 16 + col - 512;
                    int mq = mq0 + wm + i * 16 + rbase;
                    float e0 = __expf(acc[i][j][0]);
                    float e1 = __expf(acc[i][j][1]);
                    float e2 = __expf(acc[i][j][2]);
                    float e3 = __expf(acc[i][j][3]);
                    cs[j] += e0 + e1 + e2 + e3;
                    us4 pk = { f2b(e0), f2b(e1), f2b(e2), f2b(e3) };
                    *(us4*)(O2 + ((long long)b * 512 + d) * 4096 + mq) = pk;
                }
#pragma unroll
            for (int j = 0; j < 4; ++j) {
                float v = cs[j];
                v += __shfl_xor(v, 16);
                v += __shfl_xor(v, 32);
                if (l < 16)
                    atomicAdd(&Sk[b * 512 + n0 + wn + j * 16 + col - 512], v);
            }
        } else {
            // v branch: plain transposed store
            const int b = arow0 >> 12;
            const int mq0 = arow0 & 4095;
#pragma unroll
            for (int i = 0; i < 4; ++i)
#pragma unroll
                for (int j = 0; j < 4; ++j) {
                    int e = n0 + wn + j * 16 + col - 1024;
                    int mq = mq0 + wm + i * 16 + rbase;
                    us4 pk = { f2b(acc[i][j][0]), f2b(acc[i][j][1]),
                               f2b(acc[i][j][2]), f2b(acc[i][j][3]) };
                    *(us4*)(O3 + ((long long)b * 512 + e) * 4096 + mq) = pk;
                }
        }
    } else if constexpr (MODE == 5) {
#pragma unroll
        for (int i = 0; i < 4; ++i) {
            int gmb = arow0 + wm + i * 16 + rbase;
            float invs[4];
#pragma unroll
            for (int r = 0; r < 4; ++r) invs[r] = scale / Sn[gmb + r];
#pragma unroll
            for (int j = 0; j < 4; ++j) {
                int gn = n0 + wn + j * 16 + col;
#pragma unroll
                for (int r = 0; r < 4; ++r) {
                    long long idx = (long long)(gmb + r) * ldo + gn;
                    ((unsigned short*)O)[idx] =
                        f2b(acc[i][j][r] * invs[r] + b2f(R[idx]));
                }
            }
        }
    } else {
#pragma unroll
        for (int i = 0; i < 4; ++i)
#pragma unroll
            for (int j = 0; j < 4; ++j) {
                int gn = n0 + wn + j * 16 + col;
                int gmb = arow0 + wm + i * 16 + rbase;
#pragma unroll
                for (int r = 0; r < 4; ++r) {
                    long long idx = (long long)(gmb + r) * ldo + gn;
                    float v = acc[i][j][r];
                    if constexpr (MODE == 0) {
                        ((unsigned short*)O)[idx] = f2b(v);
                    } else {
                        ((float*)O)[idx] = v + b2f(R[idx]);
                    }
                }
            }
    }
}

// ---------------------------------------------------------------------------
// ctx split-K gemm (BK=64): partial of ctxT'[b,e,d] = sum_n vT[b,e,n]*ek[b,d,n]
// split-K=4 (K=1024/block). 512 blocks, XCD-pinned per (b,s) K-slice.
// ---------------------------------------------------------------------------
__global__ __launch_bounds__(256, 4) void ctx_gemm_sk(
    const unsigned short* __restrict__ V, const unsigned short* __restrict__ Kt,
    float* __restrict__ P)
{
    __shared__ __attribute__((aligned(16))) unsigned short As[128 * 64];
    __shared__ __attribute__((aligned(16))) unsigned short Bs[128 * 64];

    const uint id = blockIdx.x;          // 0..511
    const uint xcd = id & 7;
    const uint g = id >> 3;              // 0..63
    const uint sub = g & 15;             // tile within (b,s)
    const int z = (int)(g >> 4) * 8 + (int)xcd;   // 0..31 = b*4+s
    const int b = z >> 2;
    const int s = z & 3;
    const int m0 = (int)(sub >> 2) * 128;
    const int n0 = (int)(sub & 3) * 128;

    const unsigned short* Ab = V  + (long long)b * 512 * 4096 + s * 1024;
    const unsigned short* Bb = Kt + (long long)b * 512 * 4096 + s * 1024;

    const int tid = threadIdx.x;
    const int l = tid & 63;
    const int w = tid >> 6;
    const int wm = (w >> 1) * 64;
    const int wn = (w & 1) * 64;

    const int srow = tid >> 3;
    const int scol = (tid & 7) * 8;
    const unsigned short* ga = Ab + (long long)(m0 + srow) * 4096 + scol;
    const unsigned short* gb = Bb + (long long)(n0 + srow) * 4096 + scol;
    unsigned short* la = As + tid * 8;
    unsigned short* lb = Bs + tid * 8;

    const int fr = l & 15;
    const int kq = (l >> 4) * 8;

    floatx4 acc[4][4] = {};

    for (int kt = 0; kt < 1024; kt += 64) {
        __syncthreads();
#pragma unroll
        for (int c = 0; c < 4; ++c) {
            g2l16(ga + (long long)(c * 32) * 4096, la + c * 2048);
            g2l16(gb + (long long)(c * 32) * 4096, lb + c * 2048);
        }
        ga += 64; gb += 64;
        __syncthreads();

#pragma unroll
        for (int h = 0; h < 2; ++h) {
            bf16x8 af[4], bfr[4];
#pragma unroll
            for (int i = 0; i < 4; ++i) {
                af[i]  = *(const bf16x8*)(As + (wm + i * 16 + fr) * 64 + kq + 32 * h);
                bfr[i] = *(const bf16x8*)(Bs + (wn + i * 16 + fr) * 64 + kq + 32 * h);
            }
#pragma unroll
            for (int i = 0; i < 4; ++i)
#pragma unroll
                for (int j = 0; j < 4; ++j)
                    acc[i][j] = __builtin_amdgcn_mfma_f32_16x16x32_bf16(
                        af[i], bfr[j], acc[i][j], 0, 0, 0);
        }
    }

    const int col = l & 15;
    const int rbase = (l >> 4) * 4;
    float* Pb = P + ((long long)z * 16 + (sub >> 2) * 4 + (sub & 3)) * 16384;
#pragma unroll
    for (int i = 0; i < 4; ++i)
#pragma unroll
        for (int j = 0; j < 4; ++j)
#pragma unroll
            for (int r = 0; r < 4; ++r)
                Pb[(wm + i * 16 + rbase + r) * 128 + wn + j * 16 + col] =
                    acc[i][j][r];
}

// Sum 4 split-K partials, normalize by k-softmax denominator Sk[b*512+d],
// store bf16 ctxT[b, e, d].
__global__ __launch_bounds__(256) void ctx_reduce(const float* __restrict__ P,
                                                  const float* __restrict__ Sk,
                                                  unsigned short* __restrict__ Ct)
{
    long long f = (long long)blockIdx.x * 256 + threadIdx.x;
    long long base = f * 4;
    int tile = (int)(base >> 14);          // (b, mt, nt)
    int lo = (int)(base & 16383);
    int b = tile >> 4;
    int mt = (tile >> 2) & 3;
    int nt = tile & 3;
    float4 s = {0.f, 0.f, 0.f, 0.f};
#pragma unroll
    for (int sp = 0; sp < 4; ++sp) {
        float4 v = *(const float4*)(P + ((long long)(b * 4 + sp) * 16 + mt * 4 + nt) * 16384 + lo);
        s.x += v.x; s.y += v.y; s.z += v.z; s.w += v.w;
    }
    int le = lo >> 7;
    int ld = lo & 127;
    float4 sk = *(const float4*)(Sk + b * 512 + nt * 128 + ld);
    us4 o = { f2b(s.x / sk.x), f2b(s.y / sk.y), f2b(s.z / sk.z), f2b(s.w / sk.w) };
    *(us4*)(Ct + (long long)b * 262144 + (mt * 128 + le) * 512 + nt * 128 + ld) = o;
}

// ---------------------------------------------------------------------------
// conversions / init
// ---------------------------------------------------------------------------
__global__ __launch_bounds__(256) void f32_to_bf16_k(const float* __restrict__ in,
                                                     unsigned short* __restrict__ out)
{
    long long i = ((long long)blockIdx.x * 256 + threadIdx.x) * 4;
    float4 v = *(const float4*)(in + i);
    us4 o = { f2b(v.x), f2b(v.y), f2b(v.z), f2b(v.w) };
    *(us4*)(out + i) = o;
}

struct WPtrs { const float* in[5]; unsigned short* out[5]; };
__global__ __launch_bounds__(256) void conv_weights(WPtrs p)
{
    int which = blockIdx.y;
    long long i = ((long long)blockIdx.x * 256 + threadIdx.x) * 4;
    float4 v = *(const float4*)(p.in[which] + i);
    us4 o = { f2b(v.x), f2b(v.y), f2b(v.z), f2b(v.w) };
    *(us4*)(p.out[which] + i) = o;
}

__global__ __launch_bounds__(256) void zero_f32(float* __restrict__ p)
{
    long long i = ((long long)blockIdx.x * 256 + threadIdx.x) * 4;
    *(float4*)(p + i) = make_float4(0.f, 0.f, 0.f, 0.f);
}

// ---------------------------------------------------------------------------
extern "C" void kernel_launch(void* const* d_in, const int* in_sizes, int n_in,
                              void* d_out, int out_size, void* d_ws, size_t ws_size,
                              hipStream_t stream)
{
    (void)in_sizes; (void)n_in; (void)out_size; (void)ws_size;
    const float* x  = (const float*)d_in[0];
    const float* Wq = (const float*)d_in[1];
    const float* Wk = (const float*)d_in[2];
    const float* Wv = (const float*)d_in[3];
    const float* W1 = (const float*)d_in[4];
    const float* W2 = (const float*)d_in[5];
    float* out = (float*)d_out;

    const int Bn = 8, N = 4096, C = 512;
    const long long M  = (long long)Bn * N;   // 32768
    const long long XE = M * C;               // 16,777,216 elements

    char* ws = (char*)d_ws;
    size_t off = 0;
    auto carve = [&](size_t bytes) -> void* {
        void* p = ws + off;
        off += (bytes + 255) & ~(size_t)255;
        return p;
    };

    unsigned short* xb   = (unsigned short*)carve(XE * 2);
    unsigned short* wcat = (unsigned short*)carve((size_t)3 * C * C * 2); // [Wq;Wk;Wv]
    unsigned short* w1b  = (unsigned short*)carve((size_t)C * C * 2);
    unsigned short* w2b  = (unsigned short*)carve((size_t)C * C * 2);
    unsigned short* q    = (unsigned short*)carve(XE * 2);   // exp(q)
    unsigned short* kT   = (unsigned short*)carve(XE * 2);   // exp(k) [b,d,n]
    unsigned short* vT   = (unsigned short*)carve(XE * 2);   // [b,e,n]
    unsigned short* ctxT = (unsigned short*)carve((size_t)Bn * C * C * 2); // [b,e,d]
    float* Ssum = (float*)carve((size_t)(M + Bn * C) * 4);   // Sq[M] ++ Sk[Bn*C]
    float* Sq = Ssum;
    float* Sk = Ssum + M;
    unsigned short* xr = kT;       // alias: kT dead after ctx gemm
    unsigned short* h  = vT;       // alias: vT dead after ctx gemm
    float* P = (float*)d_out;      // split-K partials: d_out is scratch until
                                   // the final gemm overwrites all of it

    // zero softmax-sum accumulators (36864 floats = 36 blocks x 256 x 4)
    zero_f32<<<dim3(36), 256, 0, stream>>>(Ssum);

    // dtype conversions
    f32_to_bf16_k<<<dim3((unsigned)(XE / 1024)), dim3(256), 0, stream>>>(x, xb);
    WPtrs wp = { { Wq, Wk, Wv, W1, W2 },
                 { wcat, wcat + C * C, wcat + 2 * C * C, w1b, w2b } };
    conv_weights<<<dim3((C * C) / 1024, 5), dim3(256), 0, stream>>>(wp);

    // fused q/k/v + exp + softmax-denominator atomics
    gemm64<4, 12, false><<<dim3(3072), 256, 0, stream>>>(
        xb, wcat, q, nullptr, kT, vT, Sq, Sk, nullptr, C, C, C, C, 0, 0.f);

    // ctxT'[b,e,d] = sum_n vT[b,e,n] * ek[b,d,n]  (split-K=4 + reduce w/ 1/Sk)
    ctx_gemm_sk<<<dim3(512), 256, 0, stream>>>(vT, kT, P);
    ctx_reduce<<<dim3(2048), 256, 0, stream>>>(P, Sk, ctxT);

    // xr[b,n,e] = (scale/Sq[n]) * sum_d eq[b,n,d]*ctxT[b,e,d] + x[b,n,e]
    gemm64<5, 4, true><<<dim3(1024), 256, 0, stream>>>(
        q, ctxT, xr, xb, nullptr, nullptr, nullptr, nullptr, Sq,
        C, C, C, C, (long long)C * C, 0.044194173824159216f);

    // h = xr @ W1.T
    gemm64<0, 4, false><<<dim3(1024), 256, 0, stream>>>(
        xr, w1b, h, nullptr, nullptr, nullptr, nullptr, nullptr, nullptr,
        C, C, C, C, 0, 0.f);

    // out = h @ W2.T + xr   (fp32 output)
    gemm64<3, 4, false><<<dim3(1024), 256, 0, stream>>>(
        h, w2b, out, xr, nullptr, nullptr, nullptr, nullptr, nullptr,
        C, C, C, C, 0, 0.f);
}